// Round 4
// baseline (236.362 us; speedup 1.0000x reference)
//
#include <hip/hip_runtime.h>
#include <hip/hip_bf16.h>

#define B_   2
#define S_   1024
#define E_   2048
#define NH_  16
#define DH_  128
#define EPS_ 1e-6f

using half8   = __attribute__((ext_vector_type(8))) _Float16;
using floatx4 = __attribute__((ext_vector_type(4))) float;

__device__ __forceinline__ half8 cvt8h(const float* __restrict__ p) {
    float4 a = *(const float4*)p;
    float4 b = *(const float4*)(p + 4);
    half8 r;
    r[0] = (_Float16)a.x; r[1] = (_Float16)a.y;
    r[2] = (_Float16)a.z; r[3] = (_Float16)a.w;
    r[4] = (_Float16)b.x; r[5] = (_Float16)b.y;
    r[6] = (_Float16)b.z; r[7] = (_Float16)b.w;
    return r;
}

// ---------------------------------------------------------------------------
// Kernel 1: gate GEMM.  x = concat(q,k,v) : (B*S, 6144) fp32 -> f16 staged.
// ig[b,h,s] = x.Wi[:,h] + bi[h];  lf[b,h,s] = log_sigmoid(x.Wf[:,h] + bf[h])
// ---------------------------------------------------------------------------
__global__ __launch_bounds__(256, 4) void gates_kernel(
    const float* __restrict__ q, const float* __restrict__ k,
    const float* __restrict__ v, const float* __restrict__ Wi,
    const float* __restrict__ bi, const float* __restrict__ Wf,
    const float* __restrict__ bfb, float* __restrict__ ig_out,
    float* __restrict__ lf_out)
{
    __shared__ __attribute__((aligned(16))) _Float16 xs[32 * 264];
    __shared__ __attribute__((aligned(16))) _Float16 wt[32 * 264];

    const int t    = threadIdx.x;
    const int w    = t >> 6, lane = t & 63, quad = lane >> 4, l15 = lane & 15;
    const int mw   = w & 1, nw = w >> 1;
    const int m0   = blockIdx.x * 32;

    floatx4 acc = {0.f, 0.f, 0.f, 0.f};

    for (int c = 0; c < 24; ++c) {
        __syncthreads();
        const int e0   = c * 256;
        const int tsel = e0 >> 11;            // 0:q 1:k 2:v
        const int el0  = e0 & 2047;
        const float* xb = (tsel == 0) ? q : (tsel == 1) ? k : v;
        #pragma unroll
        for (int i = 0; i < 4; ++i) {
            int g = t + i * 256;
            int row = g >> 5, grp = g & 31;
            half8 s8 = cvt8h(xb + (size_t)(m0 + row) * E_ + el0 + grp * 8);
            *(half8*)(&xs[row * 264 + grp * 8]) = s8;
        }
        {   // W chunk transposed: thread t owns k-row (e0+t); 16 heads each of Wi,Wf
            const int kk = t;
            const float* wiRow = Wi + (size_t)(e0 + kk) * NH_;
            const float* wfRow = Wf + (size_t)(e0 + kk) * NH_;
            float wif[16], wff[16];
            #pragma unroll
            for (int i4 = 0; i4 < 4; ++i4) {
                float4 a = *(const float4*)(wiRow + i4 * 4);
                wif[i4*4+0]=a.x; wif[i4*4+1]=a.y; wif[i4*4+2]=a.z; wif[i4*4+3]=a.w;
                float4 b = *(const float4*)(wfRow + i4 * 4);
                wff[i4*4+0]=b.x; wff[i4*4+1]=b.y; wff[i4*4+2]=b.z; wff[i4*4+3]=b.w;
            }
            #pragma unroll
            for (int hh = 0; hh < 16; ++hh) wt[hh * 264 + kk]        = (_Float16)wif[hh];
            #pragma unroll
            for (int hh = 0; hh < 16; ++hh) wt[(16 + hh) * 264 + kk] = (_Float16)wff[hh];
        }
        __syncthreads();
        #pragma unroll
        for (int ks = 0; ks < 8; ++ks) {
            half8 af = *(const half8*)(&xs[(mw * 16 + l15) * 264 + ks * 32 + quad * 8]);
            half8 bw = *(const half8*)(&wt[(nw * 16 + l15) * 264 + ks * 32 + quad * 8]);
            acc = __builtin_amdgcn_mfma_f32_16x16x32_f16(af, bw, acc, 0, 0, 0);
        }
    }
    #pragma unroll
    for (int reg = 0; reg < 4; ++reg) {
        int m   = m0 + mw * 16 + quad * 4 + reg;
        int b   = m >> 10, s = m & 1023;
        int col = nw * 16 + l15;
        float vacc = acc[reg];
        if (col < 16) {
            int h = col;
            ig_out[((size_t)(b * NH_ + h)) * S_ + s] = vacc + bi[h];
        } else {
            int h = col - 16;
            float x = vacc + bfb[h];
            float ls = (x >= 0.f) ? -log1pf(__expf(-x)) : (x - log1pf(__expf(x)));
            lf_out[((size_t)(b * NH_ + h)) * S_ + s] = ls;
        }
    }
}

// ---------------------------------------------------------------------------
// Kernel 2: per-(b,h) scans, IN PLACE: Aj overwrites ig, Cq overwrites lf.
// F = cumsum(lf), M = runmax(ig - F).  Aj[j]=ig-F, Cq[i]=-M[i], NF[i]=exp(-(F+M)).
// ---------------------------------------------------------------------------
__global__ void scan_kernel(float* __restrict__ igAj, float* __restrict__ lfCq,
                            float* __restrict__ NFo)
{
    const int bh   = blockIdx.x;
    const int lane = threadIdx.x;
    float* igp = igAj + (size_t)bh * S_;
    float* lfp = lfCq + (size_t)bh * S_;
    float carryF = 0.f, carryM = -3.0e38f;
    for (int it = 0; it < 16; ++it) {
        int idx = it * 64 + lane;
        float lfv = lfp[idx];
        float igv = igp[idx];
        float sc = lfv;
        #pragma unroll
        for (int off = 1; off < 64; off <<= 1) {
            float o = __shfl_up(sc, off);
            if (lane >= off) sc += o;
        }
        float F = carryF + sc;
        float a = igv - F;
        float ms = a;
        #pragma unroll
        for (int off = 1; off < 64; off <<= 1) {
            float o = __shfl_up(ms, off);
            if (lane >= off) ms = fmaxf(ms, o);
        }
        float M = fmaxf(carryM, ms);
        igp[idx] = a;                               // Aj
        lfp[idx] = -M;                              // Cq
        NFo[(size_t)bh * S_ + idx] = expf(fminf(-(F + M), 80.f));
        carryF = __shfl(F, 63);
        carryM = __shfl(M, 63);
    }
}

// ---------------------------------------------------------------------------
// Kernel 3: fused causal attention + normalizer + per-head LayerNorm.
// Block = (q-tile of 64 rows) x (b,h); 4 waves; TK=64.  fp32 in, fp32 out,
// f16 MFMA internally (fp32 accumulate).
// ---------------------------------------------------------------------------
__global__ __launch_bounds__(256, 2) void attn_kernel(
    const float* __restrict__ q, const float* __restrict__ k,
    const float* __restrict__ v, const float* __restrict__ Aj,
    const float* __restrict__ Cq, const float* __restrict__ NFi,
    const float* __restrict__ lnsc, float* __restrict__ out)
{
    __shared__ __attribute__((aligned(16))) _Float16 Qs[64 * 136];
    __shared__ __attribute__((aligned(16))) _Float16 Ks[64 * 136];
    __shared__ __attribute__((aligned(16))) _Float16 Vt[128 * 72];
    __shared__ __attribute__((aligned(16))) _Float16 Pb[64 * 72];
    __shared__ float aj[64], ci[64], nfv[64], lns[128];

    const int t    = threadIdx.x;
    const int w    = t >> 6, lane = t & 63, quad = lane >> 4, l15 = lane & 15;
    const int qi   = blockIdx.x, bh = blockIdx.y;
    const int b    = bh >> 4, h = bh & 15;
    const size_t rowbase = (size_t)b * S_;
    const int q0   = qi * 64;

    if (t < 64) {
        ci[t]  = Cq[(size_t)bh * S_ + q0 + t];
        nfv[t] = NFi[(size_t)bh * S_ + q0 + t];
    } else if (t < 192) {
        int d = t - 64;
        lns[d] = lnsc[h * DH_ + d];
    }
    #pragma unroll
    for (int i = 0; i < 4; ++i) {
        int g = t + i * 256;
        int row = g >> 4, grp = g & 15;
        half8 s8 = cvt8h(q + (rowbase + q0 + row) * E_ + h * DH_ + grp * 8);
        *(half8*)(&Qs[row * 136 + grp * 8]) = s8;
    }
    __syncthreads();
    half8 aq[4];
    #pragma unroll
    for (int ks = 0; ks < 4; ++ks)
        aq[ks] = *(const half8*)(&Qs[(w * 16 + l15) * 136 + ks * 32 + quad * 8]);
    float ci_r[4];
    #pragma unroll
    for (int reg = 0; reg < 4; ++reg) ci_r[reg] = ci[w * 16 + quad * 4 + reg];

    floatx4 acc_h[8];
    #pragma unroll
    for (int i = 0; i < 8; ++i) acc_h[i] = (floatx4){0.f, 0.f, 0.f, 0.f};
    float lrun[4] = {0.f, 0.f, 0.f, 0.f};
    const float rscale = 0.08838834764831845f;   // 1/sqrt(128)

    for (int kt = 0; kt <= qi; ++kt) {
        __syncthreads();
        const int j0 = kt * 64;
        #pragma unroll
        for (int i = 0; i < 4; ++i) {
            int g = t + i * 256;
            int row = g >> 4, grp = g & 15;
            size_t goff = (rowbase + j0 + row) * E_ + h * DH_ + grp * 8;
            half8 kv8 = cvt8h(k + goff);
            *(half8*)(&Ks[row * 136 + grp * 8]) = kv8;
            float4 va = *(const float4*)(v + goff);
            float4 vb = *(const float4*)(v + goff + 4);
            _Float16 vs[8];
            vs[0]=(_Float16)va.x; vs[1]=(_Float16)va.y; vs[2]=(_Float16)va.z; vs[3]=(_Float16)va.w;
            vs[4]=(_Float16)vb.x; vs[5]=(_Float16)vb.y; vs[6]=(_Float16)vb.z; vs[7]=(_Float16)vb.w;
            #pragma unroll
            for (int uu = 0; uu < 8; ++uu) {      // lane-rotated scatter: 2-way banks
                int u = (uu + lane) & 7;
                Vt[(grp * 8 + u) * 72 + row] = vs[u];
            }
        }
        if (t < 64) aj[t] = Aj[(size_t)bh * S_ + j0 + t];
        __syncthreads();

        floatx4 sacc[4];
        #pragma unroll
        for (int nt = 0; nt < 4; ++nt) sacc[nt] = (floatx4){0.f, 0.f, 0.f, 0.f};
        #pragma unroll
        for (int ks = 0; ks < 4; ++ks) {
            #pragma unroll
            for (int nt = 0; nt < 4; ++nt) {
                half8 bk = *(const half8*)(&Ks[(nt * 16 + l15) * 136 + ks * 32 + quad * 8]);
                sacc[nt] = __builtin_amdgcn_mfma_f32_16x16x32_f16(aq[ks], bk, sacc[nt], 0, 0, 0);
            }
        }
        const bool diag = (kt == qi);
        #pragma unroll
        for (int nt = 0; nt < 4; ++nt) {
            int jl = nt * 16 + l15;
            float a_j = aj[jl];
            #pragma unroll
            for (int reg = 0; reg < 4; ++reg) {
                int rl = w * 16 + quad * 4 + reg;
                float p = 0.f;
                if (!diag || (jl <= rl))
                    p = sacc[nt][reg] * rscale * __expf(fminf(ci_r[reg] + a_j, 0.f));
                lrun[reg] += p;
                Pb[rl * 72 + jl] = (_Float16)p;
            }
        }
        __syncthreads();
        #pragma unroll
        for (int ks2 = 0; ks2 < 2; ++ks2) {
            half8 ap = *(const half8*)(&Pb[(w * 16 + l15) * 72 + ks2 * 32 + quad * 8]);
            #pragma unroll
            for (int nt2 = 0; nt2 < 8; ++nt2) {
                half8 bv = *(const half8*)(&Vt[(nt2 * 16 + l15) * 72 + ks2 * 32 + quad * 8]);
                acc_h[nt2] = __builtin_amdgcn_mfma_f32_16x16x32_f16(ap, bv, acc_h[nt2], 0, 0, 0);
            }
        }
    }

    #pragma unroll
    for (int reg = 0; reg < 4; ++reg) {
        float l = lrun[reg];
        #pragma unroll
        for (int off = 1; off < 16; off <<= 1) l += __shfl_xor(l, off);
        int rl = w * 16 + quad * 4 + reg;
        float nrm = fmaxf(fabsf(l), nfv[rl]) + EPS_;
        float inv = 1.f / nrm;
        float hv[8];
        float sum = 0.f, sq = 0.f;
        #pragma unroll
        for (int nt2 = 0; nt2 < 8; ++nt2) {
            float x = acc_h[nt2][reg] * inv;
            hv[nt2] = x; sum += x; sq += x * x;
        }
        #pragma unroll
        for (int off = 1; off < 16; off <<= 1) {
            sum += __shfl_xor(sum, off);
            sq  += __shfl_xor(sq, off);
        }
        float mean = sum * (1.f / 128.f);
        float var  = fmaxf(sq * (1.f / 128.f) - mean * mean, 0.f);
        float rstd = rsqrtf(var + EPS_);
        size_t orow = (rowbase + q0 + rl) * E_ + h * DH_;
        #pragma unroll
        for (int nt2 = 0; nt2 < 8; ++nt2) {
            int d = nt2 * 16 + l15;
            out[orow + d] = (hv[nt2] - mean) * rstd * lns[d];
        }
    }
}

// ---------------------------------------------------------------------------
extern "C" void kernel_launch(void* const* d_in, const int* in_sizes, int n_in,
                              void* d_out, int out_size, void* d_ws, size_t ws_size,
                              hipStream_t stream)
{
    const float* q    = (const float*)d_in[0];
    const float* k    = (const float*)d_in[1];
    const float* v    = (const float*)d_in[2];
    const float* Wi   = (const float*)d_in[3];
    const float* bi   = (const float*)d_in[4];
    const float* Wf   = (const float*)d_in[5];
    const float* bfb  = (const float*)d_in[6];
    const float* lnsc = (const float*)d_in[7];
    float* out        = (float*)d_out;

    const int NS = B_ * NH_ * S_;   // 32768
    float* igAj = (float*)d_ws;          // gates: ig  -> scan rewrites to Aj
    float* lfCq = igAj + NS;             // gates: lf  -> scan rewrites to Cq
    float* NFa  = lfCq + NS;             // scan: exp(-max_log_D)

    gates_kernel<<<dim3(64), 256, 0, stream>>>(q, k, v, Wi, bi, Wf, bfb, igAj, lfCq);
    scan_kernel<<<dim3(32), 64, 0, stream>>>(igAj, lfCq, NFa);
    attn_kernel<<<dim3(16, 32), 256, 0, stream>>>(q, k, v, igAj, lfCq, NFa, lnsc, out);
}

// Round 5
// 199.505 us; speedup vs baseline: 1.1847x; 1.1847x over previous
//
#include <hip/hip_runtime.h>
#include <hip/hip_bf16.h>

#define B_   2
#define S_   1024
#define E_   2048
#define NH_  16
#define DH_  128
#define EPS_ 1e-6f

using half8   = __attribute__((ext_vector_type(8))) _Float16;
using floatx4 = __attribute__((ext_vector_type(4))) float;

__device__ __forceinline__ half8 cvt8h(const float* __restrict__ p) {
    float4 a = *(const float4*)p;
    float4 b = *(const float4*)(p + 4);
    half8 r;
    r[0] = (_Float16)a.x; r[1] = (_Float16)a.y;
    r[2] = (_Float16)a.z; r[3] = (_Float16)a.w;
    r[4] = (_Float16)b.x; r[5] = (_Float16)b.y;
    r[6] = (_Float16)b.z; r[7] = (_Float16)b.w;
    return r;
}

// ---------------------------------------------------------------------------
// Kernel 1: gate GEMM, K-split x8 with fp32 atomic accumulation.
// grid (64,8): x = 32-row group, y = K-split (768 K each, 3 chunks of 256).
// Emits PRE-activations (no bias): pre_i/pre_f [b*NH+h][s], zeroed beforehand.
// ---------------------------------------------------------------------------
__global__ __launch_bounds__(256, 4) void gates_kernel(
    const float* __restrict__ q, const float* __restrict__ k,
    const float* __restrict__ v, const float* __restrict__ Wi,
    const float* __restrict__ Wf, float* __restrict__ pre_i,
    float* __restrict__ pre_f)
{
    __shared__ __attribute__((aligned(16))) _Float16 xs[32 * 264];
    __shared__ __attribute__((aligned(16))) _Float16 wt[32 * 264];

    const int t    = threadIdx.x;
    const int w    = t >> 6, lane = t & 63, quad = lane >> 4, l15 = lane & 15;
    const int mw   = w & 1, nw = w >> 1;
    const int m0   = blockIdx.x * 32;
    const int kbase = blockIdx.y * 768;

    floatx4 acc = {0.f, 0.f, 0.f, 0.f};

    for (int c = 0; c < 3; ++c) {
        __syncthreads();
        const int e0   = kbase + c * 256;
        const int tsel = e0 >> 11;            // 0:q 1:k 2:v (256 | boundaries)
        const int el0  = e0 & 2047;
        const float* xb = (tsel == 0) ? q : (tsel == 1) ? k : v;
        #pragma unroll
        for (int i = 0; i < 4; ++i) {
            int g = t + i * 256;
            int row = g >> 5, grp = g & 31;
            half8 s8 = cvt8h(xb + (size_t)(m0 + row) * E_ + el0 + grp * 8);
            *(half8*)(&xs[row * 264 + grp * 8]) = s8;
        }
        {   // W chunk transposed: thread t owns k-row (e0+t)
            const int kk = t;
            const float* wiRow = Wi + (size_t)(e0 + kk) * NH_;
            const float* wfRow = Wf + (size_t)(e0 + kk) * NH_;
            float wif[16], wff[16];
            #pragma unroll
            for (int i4 = 0; i4 < 4; ++i4) {
                float4 a = *(const float4*)(wiRow + i4 * 4);
                wif[i4*4+0]=a.x; wif[i4*4+1]=a.y; wif[i4*4+2]=a.z; wif[i4*4+3]=a.w;
                float4 b = *(const float4*)(wfRow + i4 * 4);
                wff[i4*4+0]=b.x; wff[i4*4+1]=b.y; wff[i4*4+2]=b.z; wff[i4*4+3]=b.w;
            }
            #pragma unroll
            for (int hh = 0; hh < 16; ++hh) wt[hh * 264 + kk]        = (_Float16)wif[hh];
            #pragma unroll
            for (int hh = 0; hh < 16; ++hh) wt[(16 + hh) * 264 + kk] = (_Float16)wff[hh];
        }
        __syncthreads();
        #pragma unroll
        for (int ks = 0; ks < 8; ++ks) {
            half8 af = *(const half8*)(&xs[(mw * 16 + l15) * 264 + ks * 32 + quad * 8]);
            half8 bw = *(const half8*)(&wt[(nw * 16 + l15) * 264 + ks * 32 + quad * 8]);
            acc = __builtin_amdgcn_mfma_f32_16x16x32_f16(af, bw, acc, 0, 0, 0);
        }
    }
    #pragma unroll
    for (int reg = 0; reg < 4; ++reg) {
        int m   = m0 + mw * 16 + quad * 4 + reg;
        int b   = m >> 10, s = m & 1023;
        int col = nw * 16 + l15;
        float vacc = acc[reg];
        if (col < 16)
            atomicAdd(&pre_i[((size_t)(b * NH_ + col)) * S_ + s], vacc);
        else
            atomicAdd(&pre_f[((size_t)(b * NH_ + col - 16)) * S_ + s], vacc);
    }
}

// ---------------------------------------------------------------------------
// Kernel 2: bias + log_sigmoid + per-(b,h) scans, IN PLACE.
// F = cumsum(logsig(pre_f+bf)), M = runmax(pre_i+bi - F).
// Aj overwrites pre_i, Cq overwrites pre_f, NF[i]=exp(-(F+M)).
// ---------------------------------------------------------------------------
__global__ void scan_kernel(float* __restrict__ igAj, float* __restrict__ lfCq,
                            float* __restrict__ NFo, const float* __restrict__ bi,
                            const float* __restrict__ bfb)
{
    const int bh   = blockIdx.x;
    const int h    = bh & 15;
    const int lane = threadIdx.x;
    float* igp = igAj + (size_t)bh * S_;
    float* lfp = lfCq + (size_t)bh * S_;
    const float bih = bi[h], bfh = bfb[h];
    float carryF = 0.f, carryM = -3.0e38f;
    for (int it = 0; it < 16; ++it) {
        int idx = it * 64 + lane;
        float x   = lfp[idx] + bfh;
        float lfv = (x >= 0.f) ? -log1pf(__expf(-x)) : (x - log1pf(__expf(x)));
        float igv = igp[idx] + bih;
        float sc = lfv;
        #pragma unroll
        for (int off = 1; off < 64; off <<= 1) {
            float o = __shfl_up(sc, off);
            if (lane >= off) sc += o;
        }
        float F = carryF + sc;
        float a = igv - F;
        float ms = a;
        #pragma unroll
        for (int off = 1; off < 64; off <<= 1) {
            float o = __shfl_up(ms, off);
            if (lane >= off) ms = fmaxf(ms, o);
        }
        float M = fmaxf(carryM, ms);
        igp[idx] = a;                               // Aj
        lfp[idx] = -M;                              // Cq
        NFo[(size_t)bh * S_ + idx] = expf(fminf(-(F + M), 80.f));
        carryF = __shfl(F, 63);
        carryM = __shfl(M, 63);
    }
}

// ---------------------------------------------------------------------------
// Kernel 3: fused causal attention + normalizer + per-head LayerNorm.
// 1-D grid of 512 with complementary qi remap (work-balance across CUs).
// Q A-frags direct from global (no Qs LDS) -> 46.3 KB LDS -> 3 blocks/CU.
// ---------------------------------------------------------------------------
__global__ __launch_bounds__(256, 3) void attn_kernel(
    const float* __restrict__ q, const float* __restrict__ k,
    const float* __restrict__ v, const float* __restrict__ Aj,
    const float* __restrict__ Cq, const float* __restrict__ NFi,
    const float* __restrict__ lnsc, float* __restrict__ out)
{
    __shared__ __attribute__((aligned(16))) _Float16 Ks[64 * 136];
    __shared__ __attribute__((aligned(16))) _Float16 Vt[128 * 72];
    __shared__ __attribute__((aligned(16))) _Float16 Pb[64 * 72];
    __shared__ float aj[64], ci[64], nfv[64], lns[128];

    const int t    = threadIdx.x;
    const int w    = t >> 6, lane = t & 63, quad = lane >> 4, l15 = lane & 15;
    const int L    = blockIdx.x;
    int qi, bh;
    if (L < 256) { qi = L >> 5;              bh = L & 31; }
    else         { qi = 15 - ((L - 256) >> 5); bh = (L - 256) & 31; }
    const int b    = bh >> 4, h = bh & 15;
    const size_t rowbase = (size_t)b * S_;
    const int q0   = qi * 64;

    if (t < 64) {
        ci[t]  = Cq[(size_t)bh * S_ + q0 + t];
        nfv[t] = NFi[(size_t)bh * S_ + q0 + t];
    } else if (t < 192) {
        int d = t - 64;
        lns[d] = lnsc[h * DH_ + d];
    }
    // Q A-frags straight from global: A[m=w*16+l15][k=ks*32+quad*8+j]
    half8 aq[4];
    {
        const float* qrow = q + (rowbase + q0 + w * 16 + l15) * E_ + h * DH_;
        #pragma unroll
        for (int ks = 0; ks < 4; ++ks)
            aq[ks] = cvt8h(qrow + ks * 32 + quad * 8);
    }
    __syncthreads();
    float ci_r[4];
    #pragma unroll
    for (int reg = 0; reg < 4; ++reg) ci_r[reg] = ci[w * 16 + quad * 4 + reg];

    floatx4 acc_h[8];
    #pragma unroll
    for (int i = 0; i < 8; ++i) acc_h[i] = (floatx4){0.f, 0.f, 0.f, 0.f};
    float lrun[4] = {0.f, 0.f, 0.f, 0.f};
    const float rscale = 0.08838834764831845f;   // 1/sqrt(128)

    for (int kt = 0; kt <= qi; ++kt) {
        __syncthreads();
        const int j0 = kt * 64;
        #pragma unroll
        for (int i = 0; i < 4; ++i) {
            int g = t + i * 256;
            int row = g >> 4, grp = g & 15;
            size_t goff = (rowbase + j0 + row) * E_ + h * DH_ + grp * 8;
            half8 kv8 = cvt8h(k + goff);
            *(half8*)(&Ks[row * 136 + grp * 8]) = kv8;
            float4 va = *(const float4*)(v + goff);
            float4 vb = *(const float4*)(v + goff + 4);
            _Float16 vs[8];
            vs[0]=(_Float16)va.x; vs[1]=(_Float16)va.y; vs[2]=(_Float16)va.z; vs[3]=(_Float16)va.w;
            vs[4]=(_Float16)vb.x; vs[5]=(_Float16)vb.y; vs[6]=(_Float16)vb.z; vs[7]=(_Float16)vb.w;
            #pragma unroll
            for (int uu = 0; uu < 8; ++uu) {      // lane-rotated scatter: 2-way banks
                int u = (uu + lane) & 7;
                Vt[(grp * 8 + u) * 72 + row] = vs[u];
            }
        }
        if (t < 64) aj[t] = Aj[(size_t)bh * S_ + j0 + t];
        __syncthreads();

        floatx4 sacc[4];
        #pragma unroll
        for (int nt = 0; nt < 4; ++nt) sacc[nt] = (floatx4){0.f, 0.f, 0.f, 0.f};
        #pragma unroll
        for (int ks = 0; ks < 4; ++ks) {
            #pragma unroll
            for (int nt = 0; nt < 4; ++nt) {
                half8 bk = *(const half8*)(&Ks[(nt * 16 + l15) * 136 + ks * 32 + quad * 8]);
                sacc[nt] = __builtin_amdgcn_mfma_f32_16x16x32_f16(aq[ks], bk, sacc[nt], 0, 0, 0);
            }
        }
        const bool diag = (kt == qi);
        #pragma unroll
        for (int nt = 0; nt < 4; ++nt) {
            int jl = nt * 16 + l15;
            float a_j = aj[jl];
            #pragma unroll
            for (int reg = 0; reg < 4; ++reg) {
                int rl = w * 16 + quad * 4 + reg;
                float p = 0.f;
                if (!diag || (jl <= rl))
                    p = sacc[nt][reg] * rscale * __expf(fminf(ci_r[reg] + a_j, 0.f));
                lrun[reg] += p;
                Pb[rl * 72 + jl] = (_Float16)p;
            }
        }
        __syncthreads();
        #pragma unroll
        for (int ks2 = 0; ks2 < 2; ++ks2) {
            half8 ap = *(const half8*)(&Pb[(w * 16 + l15) * 72 + ks2 * 32 + quad * 8]);
            #pragma unroll
            for (int nt2 = 0; nt2 < 8; ++nt2) {
                half8 bv = *(const half8*)(&Vt[(nt2 * 16 + l15) * 72 + ks2 * 32 + quad * 8]);
                acc_h[nt2] = __builtin_amdgcn_mfma_f32_16x16x32_f16(ap, bv, acc_h[nt2], 0, 0, 0);
            }
        }
    }

    #pragma unroll
    for (int reg = 0; reg < 4; ++reg) {
        float l = lrun[reg];
        #pragma unroll
        for (int off = 1; off < 16; off <<= 1) l += __shfl_xor(l, off);
        int rl = w * 16 + quad * 4 + reg;
        float nrm = fmaxf(fabsf(l), nfv[rl]) + EPS_;
        float inv = 1.f / nrm;
        float hv[8];
        float sum = 0.f, sq = 0.f;
        #pragma unroll
        for (int nt2 = 0; nt2 < 8; ++nt2) {
            float x = acc_h[nt2][reg] * inv;
            hv[nt2] = x; sum += x; sq += x * x;
        }
        #pragma unroll
        for (int off = 1; off < 16; off <<= 1) {
            sum += __shfl_xor(sum, off);
            sq  += __shfl_xor(sq, off);
        }
        float mean = sum * (1.f / 128.f);
        float var  = fmaxf(sq * (1.f / 128.f) - mean * mean, 0.f);
        float rstd = rsqrtf(var + EPS_);
        size_t orow = (rowbase + q0 + rl) * E_ + h * DH_;
        #pragma unroll
        for (int nt2 = 0; nt2 < 8; ++nt2) {
            int d = nt2 * 16 + l15;
            out[orow + d] = (hv[nt2] - mean) * rstd * lns[d];
        }
    }
}

// ---------------------------------------------------------------------------
extern "C" void kernel_launch(void* const* d_in, const int* in_sizes, int n_in,
                              void* d_out, int out_size, void* d_ws, size_t ws_size,
                              hipStream_t stream)
{
    const float* q    = (const float*)d_in[0];
    const float* k    = (const float*)d_in[1];
    const float* v    = (const float*)d_in[2];
    const float* Wi   = (const float*)d_in[3];
    const float* bi   = (const float*)d_in[4];
    const float* Wf   = (const float*)d_in[5];
    const float* bfb  = (const float*)d_in[6];
    const float* lnsc = (const float*)d_in[7];
    float* out        = (float*)d_out;

    const int NS = B_ * NH_ * S_;   // 32768
    float* igAj = (float*)d_ws;          // gates: pre_i -> scan rewrites to Aj
    float* lfCq = igAj + NS;             // gates: pre_f -> scan rewrites to Cq
    float* NFa  = lfCq + NS;             // scan: exp(-max_log_D)

    hipMemsetAsync(d_ws, 0, 2 * (size_t)NS * sizeof(float), stream);
    gates_kernel<<<dim3(64, 8), 256, 0, stream>>>(q, k, v, Wi, Wf, igAj, lfCq);
    scan_kernel<<<dim3(32), 64, 0, stream>>>(igAj, lfCq, NFa, bi, bfb);
    attn_kernel<<<dim3(512), 256, 0, stream>>>(q, k, v, igAj, lfCq, NFa, lnsc, out);
}

// Round 6
// 180.296 us; speedup vs baseline: 1.3110x; 1.1065x over previous
//
#include <hip/hip_runtime.h>
#include <hip/hip_bf16.h>

#define B_   2
#define S_   1024
#define E_   2048
#define NH_  16
#define DH_  128
#define EPS_ 1e-6f

using half8   = __attribute__((ext_vector_type(8))) _Float16;
using floatx4 = __attribute__((ext_vector_type(4))) float;

__device__ __forceinline__ half8 cvt8h(const float* __restrict__ p) {
    float4 a = *(const float4*)p;
    float4 b = *(const float4*)(p + 4);
    half8 r;
    r[0] = (_Float16)a.x; r[1] = (_Float16)a.y;
    r[2] = (_Float16)a.z; r[3] = (_Float16)a.w;
    r[4] = (_Float16)b.x; r[5] = (_Float16)b.y;
    r[6] = (_Float16)b.z; r[7] = (_Float16)b.w;
    return r;
}

// ---------------------------------------------------------------------------
// Kernel 1: gate GEMM, K-split x8 with fp32 atomic accumulation.
// ---------------------------------------------------------------------------
__global__ __launch_bounds__(256, 4) void gates_kernel(
    const float* __restrict__ q, const float* __restrict__ k,
    const float* __restrict__ v, const float* __restrict__ Wi,
    const float* __restrict__ Wf, float* __restrict__ pre_i,
    float* __restrict__ pre_f)
{
    __shared__ __attribute__((aligned(16))) _Float16 xs[32 * 264];
    __shared__ __attribute__((aligned(16))) _Float16 wt[32 * 264];

    const int t    = threadIdx.x;
    const int w    = t >> 6, lane = t & 63, quad = lane >> 4, l15 = lane & 15;
    const int mw   = w & 1, nw = w >> 1;
    const int m0   = blockIdx.x * 32;
    const int kbase = blockIdx.y * 768;

    floatx4 acc = {0.f, 0.f, 0.f, 0.f};

    for (int c = 0; c < 3; ++c) {
        __syncthreads();
        const int e0   = kbase + c * 256;
        const int tsel = e0 >> 11;            // 0:q 1:k 2:v
        const int el0  = e0 & 2047;
        const float* xb = (tsel == 0) ? q : (tsel == 1) ? k : v;
        #pragma unroll
        for (int i = 0; i < 4; ++i) {
            int g = t + i * 256;
            int row = g >> 5, grp = g & 31;
            half8 s8 = cvt8h(xb + (size_t)(m0 + row) * E_ + el0 + grp * 8);
            *(half8*)(&xs[row * 264 + grp * 8]) = s8;
        }
        {
            const int kk = t;
            const float* wiRow = Wi + (size_t)(e0 + kk) * NH_;
            const float* wfRow = Wf + (size_t)(e0 + kk) * NH_;
            float wif[16], wff[16];
            #pragma unroll
            for (int i4 = 0; i4 < 4; ++i4) {
                float4 a = *(const float4*)(wiRow + i4 * 4);
                wif[i4*4+0]=a.x; wif[i4*4+1]=a.y; wif[i4*4+2]=a.z; wif[i4*4+3]=a.w;
                float4 b = *(const float4*)(wfRow + i4 * 4);
                wff[i4*4+0]=b.x; wff[i4*4+1]=b.y; wff[i4*4+2]=b.z; wff[i4*4+3]=b.w;
            }
            #pragma unroll
            for (int hh = 0; hh < 16; ++hh) wt[hh * 264 + kk]        = (_Float16)wif[hh];
            #pragma unroll
            for (int hh = 0; hh < 16; ++hh) wt[(16 + hh) * 264 + kk] = (_Float16)wff[hh];
        }
        __syncthreads();
        #pragma unroll
        for (int ks = 0; ks < 8; ++ks) {
            half8 af = *(const half8*)(&xs[(mw * 16 + l15) * 264 + ks * 32 + quad * 8]);
            half8 bw = *(const half8*)(&wt[(nw * 16 + l15) * 264 + ks * 32 + quad * 8]);
            acc = __builtin_amdgcn_mfma_f32_16x16x32_f16(af, bw, acc, 0, 0, 0);
        }
    }
    #pragma unroll
    for (int reg = 0; reg < 4; ++reg) {
        int m   = m0 + mw * 16 + quad * 4 + reg;
        int b   = m >> 10, s = m & 1023;
        int col = nw * 16 + l15;
        float vacc = acc[reg];
        if (col < 16)
            atomicAdd(&pre_i[((size_t)(b * NH_ + col)) * S_ + s], vacc);
        else
            atomicAdd(&pre_f[((size_t)(b * NH_ + col - 16)) * S_ + s], vacc);
    }
}

// ---------------------------------------------------------------------------
// Kernel 2: bias + log_sigmoid + scans, IN PLACE, software-pipelined loads.
// ---------------------------------------------------------------------------
__global__ void scan_kernel(float* __restrict__ igAj, float* __restrict__ lfCq,
                            float* __restrict__ NFo, const float* __restrict__ bi,
                            const float* __restrict__ bfb)
{
    const int bh   = blockIdx.x;
    const int h    = bh & 15;
    const int lane = threadIdx.x;
    float* igp = igAj + (size_t)bh * S_;
    float* lfp = lfCq + (size_t)bh * S_;
    const float bih = bi[h], bfh = bfb[h];
    float carryF = 0.f, carryM = -3.0e38f;
    float lf_n = lfp[lane], ig_n = igp[lane];
    for (int it = 0; it < 16; ++it) {
        int idx = it * 64 + lane;
        float lf_c = lf_n, ig_c = ig_n;
        if (it < 15) { lf_n = lfp[idx + 64]; ig_n = igp[idx + 64]; }
        float x   = lf_c + bfh;
        float lfv = (x >= 0.f) ? -log1pf(__expf(-x)) : (x - log1pf(__expf(x)));
        float igv = ig_c + bih;
        float sc = lfv;
        #pragma unroll
        for (int off = 1; off < 64; off <<= 1) {
            float o = __shfl_up(sc, off);
            if (lane >= off) sc += o;
        }
        float F = carryF + sc;
        float a = igv - F;
        float ms = a;
        #pragma unroll
        for (int off = 1; off < 64; off <<= 1) {
            float o = __shfl_up(ms, off);
            if (lane >= off) ms = fmaxf(ms, o);
        }
        float M = fmaxf(carryM, ms);
        igp[idx] = a;                               // Aj
        lfp[idx] = -M;                              // Cq
        NFo[(size_t)bh * S_ + idx] = expf(fminf(-(F + M), 80.f));
        carryF = __shfl(F, 63);
        carryM = __shfl(M, 63);
    }
}

// ---------------------------------------------------------------------------
// Kernel 3: fused causal attention, register-prefetch pipelined K-loop.
// Global loads for tile kt+1 issued before consuming tile kt (cp.async-style);
// Vt double-buffered (the one WAR hazard), Ks/Pb single (safe across barriers).
// ---------------------------------------------------------------------------
__global__ __launch_bounds__(256, 2) void attn_kernel(
    const float* __restrict__ q, const float* __restrict__ k,
    const float* __restrict__ v, const float* __restrict__ Aj,
    const float* __restrict__ Cq, const float* __restrict__ NFi,
    const float* __restrict__ lnsc, float* __restrict__ out)
{
    __shared__ __attribute__((aligned(16))) _Float16 Ks[64 * 136];
    __shared__ __attribute__((aligned(16))) _Float16 Vt[2][128 * 72];
    __shared__ __attribute__((aligned(16))) _Float16 Pb[64 * 72];
    __shared__ float aj[64], ci[64], nfv[64], lns[128];

    const int t    = threadIdx.x;
    const int w    = t >> 6, lane = t & 63, quad = lane >> 4, l15 = lane & 15;
    const int L    = blockIdx.x;
    int qi, bh;
    if (L < 256) { qi = L >> 5;                bh = L & 31; }
    else         { qi = 15 - ((L - 256) >> 5); bh = (L - 256) & 31; }
    const int b    = bh >> 4, h = bh & 15;
    const size_t rowbase = (size_t)b * S_;
    const int q0   = qi * 64;
    const int srow = t >> 4, sgrp = t & 15;     // staging row/group (i-th adds 16 rows)

    if (t < 64) {
        ci[t]  = Cq[(size_t)bh * S_ + q0 + t];
        nfv[t] = NFi[(size_t)bh * S_ + q0 + t];
    } else if (t < 192) {
        int d = t - 64;
        lns[d] = lnsc[h * DH_ + d];
    }
    // Q A-frags straight from global: A[m=w*16+l15][k=ks*32+quad*8+j]
    half8 aq[4];
    {
        const float* qrow = q + (rowbase + q0 + w * 16 + l15) * E_ + h * DH_;
        #pragma unroll
        for (int ks = 0; ks < 4; ++ks)
            aq[ks] = cvt8h(qrow + ks * 32 + quad * 8);
    }

    // ---- prefetch tile 0 into registers ----
    half8 kreg[4], vreg[4];
    float ajreg = 0.f;
    #pragma unroll
    for (int i = 0; i < 4; ++i) {
        size_t goff = (rowbase + (srow + i * 16)) * E_ + h * DH_ + sgrp * 8;
        kreg[i] = cvt8h(k + goff);
        vreg[i] = cvt8h(v + goff);
    }
    if (t < 64) ajreg = Aj[(size_t)bh * S_ + t];

    // ---- stage tile 0 into LDS ----
    #pragma unroll
    for (int i = 0; i < 4; ++i) {
        int row = srow + i * 16;
        *(half8*)(&Ks[row * 136 + sgrp * 8]) = kreg[i];
        #pragma unroll
        for (int uu = 0; uu < 8; ++uu) {
            int u = (uu + lane) & 7;
            Vt[0][(sgrp * 8 + u) * 72 + row] = vreg[i][u];
        }
    }
    if (t < 64) aj[t] = ajreg;
    __syncthreads();

    float ci_r[4];
    #pragma unroll
    for (int reg = 0; reg < 4; ++reg) ci_r[reg] = ci[w * 16 + quad * 4 + reg];

    floatx4 acc_h[8];
    #pragma unroll
    for (int i = 0; i < 8; ++i) acc_h[i] = (floatx4){0.f, 0.f, 0.f, 0.f};
    float lrun[4] = {0.f, 0.f, 0.f, 0.f};
    const float rscale = 0.08838834764831845f;   // 1/sqrt(128)

    for (int kt = 0; kt <= qi; ++kt) {
        const int vb = kt & 1;
        // issue next-tile global loads (latency hidden behind QK+P+PV)
        if (kt < qi) {
            const int j0n = (kt + 1) * 64;
            #pragma unroll
            for (int i = 0; i < 4; ++i) {
                size_t goff = (rowbase + j0n + (srow + i * 16)) * E_ + h * DH_ + sgrp * 8;
                kreg[i] = cvt8h(k + goff);
                vreg[i] = cvt8h(v + goff);
            }
            if (t < 64) ajreg = Aj[(size_t)bh * S_ + j0n + t];
        }

        // S = Q.K^T
        floatx4 sacc[4];
        #pragma unroll
        for (int nt = 0; nt < 4; ++nt) sacc[nt] = (floatx4){0.f, 0.f, 0.f, 0.f};
        #pragma unroll
        for (int ks = 0; ks < 4; ++ks) {
            #pragma unroll
            for (int nt = 0; nt < 4; ++nt) {
                half8 bk = *(const half8*)(&Ks[(nt * 16 + l15) * 136 + ks * 32 + quad * 8]);
                sacc[nt] = __builtin_amdgcn_mfma_f32_16x16x32_f16(aq[ks], bk, sacc[nt], 0, 0, 0);
            }
        }
        // P = qk * exp(c_i + a_j), causal mask on diagonal tile
        const bool diag = (kt == qi);
        #pragma unroll
        for (int nt = 0; nt < 4; ++nt) {
            int jl = nt * 16 + l15;
            float a_j = aj[jl];
            #pragma unroll
            for (int reg = 0; reg < 4; ++reg) {
                int rl = w * 16 + quad * 4 + reg;
                float p = 0.f;
                if (!diag || (jl <= rl))
                    p = sacc[nt][reg] * rscale * __expf(fminf(ci_r[reg] + a_j, 0.f));
                lrun[reg] += p;
                Pb[rl * 72 + jl] = (_Float16)p;
            }
        }
        __syncthreads();   // Pb visible; all Ks/aj reads of tile kt complete

        // H += P.V
        #pragma unroll
        for (int ks2 = 0; ks2 < 2; ++ks2) {
            half8 ap = *(const half8*)(&Pb[(w * 16 + l15) * 72 + ks2 * 32 + quad * 8]);
            #pragma unroll
            for (int nt2 = 0; nt2 < 8; ++nt2) {
                half8 bv = *(const half8*)(&Vt[vb][(nt2 * 16 + l15) * 72 + ks2 * 32 + quad * 8]);
                acc_h[nt2] = __builtin_amdgcn_mfma_f32_16x16x32_f16(ap, bv, acc_h[nt2], 0, 0, 0);
            }
        }

        // stage tile kt+1 (Ks safe: reads done by barrier above; Vt: other buffer)
        if (kt < qi) {
            #pragma unroll
            for (int i = 0; i < 4; ++i) {
                int row = srow + i * 16;
                *(half8*)(&Ks[row * 136 + sgrp * 8]) = kreg[i];
                #pragma unroll
                for (int uu = 0; uu < 8; ++uu) {
                    int u = (uu + lane) & 7;
                    Vt[vb ^ 1][(sgrp * 8 + u) * 72 + row] = vreg[i][u];
                }
            }
            if (t < 64) aj[t] = ajreg;
            __syncthreads();   // staging kt+1 visible; all PV reads of kt complete
        }
    }

    // epilogue: normalizer + per-head LayerNorm over DH
    #pragma unroll
    for (int reg = 0; reg < 4; ++reg) {
        float l = lrun[reg];
        #pragma unroll
        for (int off = 1; off < 16; off <<= 1) l += __shfl_xor(l, off);
        int rl = w * 16 + quad * 4 + reg;
        float nrm = fmaxf(fabsf(l), nfv[rl]) + EPS_;
        float inv = 1.f / nrm;
        float hv[8];
        float sum = 0.f, sq = 0.f;
        #pragma unroll
        for (int nt2 = 0; nt2 < 8; ++nt2) {
            float x = acc_h[nt2][reg] * inv;
            hv[nt2] = x; sum += x; sq += x * x;
        }
        #pragma unroll
        for (int off = 1; off < 16; off <<= 1) {
            sum += __shfl_xor(sum, off);
            sq  += __shfl_xor(sq, off);
        }
        float mean = sum * (1.f / 128.f);
        float var  = fmaxf(sq * (1.f / 128.f) - mean * mean, 0.f);
        float rstd = rsqrtf(var + EPS_);
        size_t orow = (rowbase + q0 + rl) * E_ + h * DH_;
        #pragma unroll
        for (int nt2 = 0; nt2 < 8; ++nt2) {
            int d = nt2 * 16 + l15;
            out[orow + d] = (hv[nt2] - mean) * rstd * lns[d];
        }
    }
}

// ---------------------------------------------------------------------------
extern "C" void kernel_launch(void* const* d_in, const int* in_sizes, int n_in,
                              void* d_out, int out_size, void* d_ws, size_t ws_size,
                              hipStream_t stream)
{
    const float* q    = (const float*)d_in[0];
    const float* k    = (const float*)d_in[1];
    const float* v    = (const float*)d_in[2];
    const float* Wi   = (const float*)d_in[3];
    const float* bi   = (const float*)d_in[4];
    const float* Wf   = (const float*)d_in[5];
    const float* bfb  = (const float*)d_in[6];
    const float* lnsc = (const float*)d_in[7];
    float* out        = (float*)d_out;

    const int NS = B_ * NH_ * S_;   // 32768
    float* igAj = (float*)d_ws;          // gates: pre_i -> scan rewrites to Aj
    float* lfCq = igAj + NS;             // gates: pre_f -> scan rewrites to Cq
    float* NFa  = lfCq + NS;             // scan: exp(-max_log_D)

    hipMemsetAsync(d_ws, 0, 2 * (size_t)NS * sizeof(float), stream);
    gates_kernel<<<dim3(64, 8), 256, 0, stream>>>(q, k, v, Wi, Wf, igAj, lfCq);
    scan_kernel<<<dim3(32), 64, 0, stream>>>(igAj, lfCq, NFa, bi, bfb);
    attn_kernel<<<dim3(512), 256, 0, stream>>>(q, k, v, igAj, lfCq, NFa, lnsc, out);
}